// Round 5
// baseline (788.181 us; speedup 1.0000x reference)
//
#include <hip/hip_runtime.h>

typedef __bf16 bf16;
typedef __bf16 bf16x4 __attribute__((ext_vector_type(4)));
typedef float  f32x4  __attribute__((ext_vector_type(4)));
typedef unsigned short u16x4 __attribute__((ext_vector_type(4)));

#define NPTS 2048
#define LD 68          // LDS row stride (64 pts + 4 pad)

// ---------- dtype sniff ----------
__global__ __launch_bounds__(256) void k_sniff(const void* poses_raw, int* flag)
{
    __shared__ int cnt;
    if (threadIdx.x == 0) cnt = 0;
    __syncthreads();
    const bf16* pb = (const bf16*)poses_raw;
    int local = 0;
    for (int i = threadIdx.x; i < 9216; i += 256) {
        float v = (float)pb[i];
        if (!(v >= -2.0f && v <= 2.0f)) local++;
    }
    atomicAdd(&cnt, local);
    __syncthreads();
    if (threadIdx.x == 0) *flag = (cnt < 64) ? 1 : 0;
}

// ---------- encoder/decoder (verified, unchanged) ----------
template<typename T, int WANT>
__global__ __launch_bounds__(128) void k_encdec_t(
    const T* __restrict__ poses, const T* __restrict__ t_ped, const T* __restrict__ w,
    const T* __restrict__ Wec1, const T* __restrict__ bec1,
    const T* __restrict__ Wec21, const T* __restrict__ bec21,
    const T* __restrict__ Wec22, const T* __restrict__ bec22,
    const T* __restrict__ Wdc1, const T* __restrict__ bdc1,
    const T* __restrict__ Wdc21, const T* __restrict__ bdc21,
    const T* __restrict__ Wdc22, const T* __restrict__ bdc22,
    T* __restrict__ out_ei, T* __restrict__ out_delta,
    T* __restrict__ out_mean, T* __restrict__ out_logvar,
    const int* __restrict__ flag)
{
    if (*flag != WANT) return;
    int n = blockIdx.x, tid = threadIdx.x;
    __shared__ float sin_[88], zbuf[8], net1[64], din[80], net2[64];
    if (tid < 72)      sin_[tid] = (float)w[n*24 + tid/3] * (float)poses[n*72 + tid];
    else if (tid < 88) sin_[tid] = (float)t_ped[tid - 72];
    __syncthreads();
    if (tid < 64) {
        float a = (float)bec1[n*64 + tid];
        const T* wr = Wec1 + (size_t)(n*64 + tid) * 88;
        for (int c = 0; c < 88; ++c) a += (float)wr[c] * sin_[c];
        net1[tid] = fmaxf(a, 0.f);
    }
    __syncthreads();
    if (tid < 8) {
        float a = (float)bec21[n*8 + tid];
        const T* wr = Wec21 + (size_t)(n*8 + tid) * 64;
        for (int c = 0; c < 64; ++c) a += (float)wr[c] * net1[c];
        out_mean[n*8 + tid] = (T)a;
        zbuf[tid] = a;
    } else if (tid < 16) {
        int o = tid - 8;
        float a = (float)bec22[n*8 + o];
        const T* wr = Wec22 + (size_t)(n*8 + o) * 64;
        for (int c = 0; c < 64; ++c) a += (float)wr[c] * net1[c];
        out_logvar[n*8 + o] = (T)a;
    }
    __syncthreads();
    if (tid < 72)      din[tid] = sin_[tid];
    else if (tid < 80) din[tid] = zbuf[tid - 72];
    __syncthreads();
    if (tid < 64) {
        float a = (float)bdc1[n*64 + tid];
        const T* wr = Wdc1 + (size_t)(n*64 + tid) * 80;
        for (int c = 0; c < 80; ++c) a += (float)wr[c] * din[c];
        net2[tid] = fmaxf(a, 0.f);
    }
    __syncthreads();
    if (tid < 32) {
        float a = (float)bdc21[n*32 + tid];
        const T* wr = Wdc21 + (size_t)(n*32 + tid) * 64;
        for (int c = 0; c < 64; ++c) a += (float)wr[c] * net2[c];
        out_ei[n*32 + tid] = (T)a;
    } else if (tid < 35) {
        int o = tid - 32;
        float a = (float)bdc22[n*3 + o];
        const T* wr = Wdc22 + (size_t)(n*3 + o) * 64;
        for (int c = 0; c < 64; ++c) a += (float)wr[c] * net2[c];
        out_delta[n*3 + o] = (T)a;
    }
}

// ---------- blend weights (verified, unchanged) ----------
template<typename T, int WANT>
__global__ __launch_bounds__(256) void k_bweights_t(
    const T* __restrict__ wpts, const T* __restrict__ nodes,
    float* __restrict__ wgt, const int* __restrict__ flag)
{
    if (*flag != WANT) return;
    int v = blockIdx.x * 256 + threadIdx.x;
    float px = (float)wpts[v*3+0], py = (float)wpts[v*3+1], pz = (float)wpts[v*3+2];
    float denom = 0.f;
    for (int n = 0; n < 128; ++n) {
        float dx = px - (float)nodes[n*3+0];
        float dy = py - (float)nodes[n*3+1];
        float dz = pz - (float)nodes[n*3+2];
        float d2 = dx*dx + dy*dy + dz*dz;
        float influ = expf(-d2 * (1.0f/0.18f)) - 0.01f;
        denom += fmaxf(influ, 0.f) + 1e-7f;
    }
    float inv = 1.f / denom;
    for (int n = 0; n < 128; ++n) {
        float dx = px - (float)nodes[n*3+0];
        float dy = py - (float)nodes[n*3+1];
        float dz = pz - (float)nodes[n*3+2];
        float d2 = dx*dx + dy*dy + dz*dz;
        float influ = expf(-d2 * (1.0f/0.18f)) - 0.01f;
        wgt[n*NPTS + v] = (influ >= 0.f) ? (fmaxf(influ, 0.f) + 1e-7f) * inv : 0.f;
    }
}

// ---------- helpers ----------
__device__ __forceinline__ f32x4 ld4(const float* p) { return *(const f32x4*)p; }
__device__ __forceinline__ f32x4 ld4(const bf16* p)
{
    bf16x4 v = *(const bf16x4*)p;
    f32x4 r;
    #pragma unroll
    for (int j = 0; j < 4; ++j) r[j] = (float)v[j];
    return r;
}
__device__ __forceinline__ f32x4 ld4_nt(const float* p)
{
    return __builtin_nontemporal_load((const f32x4*)p);
}
__device__ __forceinline__ f32x4 ld4_nt(const bf16* p)
{
    u16x4 u = __builtin_nontemporal_load((const u16x4*)p);
    f32x4 r;
    #pragma unroll
    for (int j = 0; j < 4; ++j) {
        unsigned int bits = ((unsigned int)u[j]) << 16;
        r[j] = __uint_as_float(bits);
    }
    return r;
}

// W1 -> padded fp32 [128][64][96], col 95 zeroed
template<typename T, int WANT>
__global__ __launch_bounds__(256) void k_w1prep(
    const T* __restrict__ Wf1, float* __restrict__ W1p, const int* __restrict__ flag)
{
    if (*flag != WANT) return;
    int n = blockIdx.x, tid = threadIdx.x;
    for (int e = tid; e < 6144; e += 256) {
        int oc = e / 96, k = e - oc*96;
        float v = (k < 95) ? (float)Wf1[(size_t)n*6080 + oc*95 + k] : 0.f;
        W1p[(size_t)n*6144 + e] = v;
    }
}

// in-place 64->64 layer: acc over rows 0..63, barrier, write rows 0..63, barrier
template<typename T>
__device__ __forceinline__ void layer64_ip(
    const T* __restrict__ W, const T* __restrict__ b,
    float* __restrict__ xs, int og, int pg)
{
    f32x4 acc[4] = {};
    #pragma unroll 4
    for (int k0 = 0; k0 < 64; k0 += 4) {
        f32x4 wv[4], xv[4];
        #pragma unroll
        for (int c = 0; c < 4; ++c) wv[c] = ld4(W + (size_t)(og*4 + c)*64 + k0);
        #pragma unroll
        for (int j = 0; j < 4; ++j) xv[j] = *(const f32x4*)&xs[(k0 + j)*LD + pg*4];
        #pragma unroll
        for (int c = 0; c < 4; ++c)
            #pragma unroll
            for (int j = 0; j < 4; ++j)
                acc[c] += xv[j] * wv[c][j];
    }
    __syncthreads();
    #pragma unroll
    for (int c = 0; c < 4; ++c) {
        float bb = (float)b[og*4 + c];
        f32x4 hv;
        #pragma unroll
        for (int r = 0; r < 4; ++r) hv[r] = fmaxf(acc[c][r] + bb, 0.f);
        *(f32x4*)&xs[(og*4 + c)*LD + pg*4] = hv;
    }
    __syncthreads();
}

// ---------- feature field v5: P=64, 32 groups x 4 nodes, in-place 26KB LDS,
//            XCD-local atomic slices ----------
template<typename T, int WANT, int W1P>
__global__ __launch_bounds__(256, 4) void k_feat_fast(
    const T* __restrict__ Wf1, const T* __restrict__ Wf2,
    const T* __restrict__ Wf3, const T* __restrict__ Wf4,
    const T* __restrict__ lc, const T* __restrict__ ei,
    const T* __restrict__ bf1, const T* __restrict__ bf2,
    const T* __restrict__ bf3, const T* __restrict__ bf4,
    const float* __restrict__ wgt, const float* __restrict__ W1p,
    int shift, float* __restrict__ slices,
    const int* __restrict__ flag)
{
    if (*flag != WANT) return;
    // XCD-aware: xcd = bid%8 owns 4 node-groups (16 nodes, ~2MB weights -> L2-resident)
    int bid = blockIdx.x;                // 0..1023
    int xcd = bid & 7;
    int i   = bid >> 3;                  // 0..127
    int g     = 4*xcd + (i >> 5);        // 0..31  (4 nodes each)
    int ptile = i & 31;                  // 0..31  (64 pts each)
    int p0  = ptile * 64;
    int tid = threadIdx.x;
    int og = tid >> 4;                   // 16 x 4 out-channels
    int pg = tid & 15;                   // 16 x 4 points

    __shared__ __attribute__((aligned(16))) float xs[96 * LD];  // 26.1 KB

    if (tid < 64) xs[95*LD + tid] = 0.f;   // K=96 zero row; never overwritten

    f32x4 fb[4][4];
    #pragma unroll
    for (int a = 0; a < 4; ++a)
        #pragma unroll
        for (int c = 0; c < 4; ++c) fb[a][c] = (f32x4){0.f,0.f,0.f,0.f};

    f32x4 lv[4];

    auto stage_load = [&](int n) {
        const T* src = lc + ((size_t)n*NPTS + p0) * 63;   // 4032 contiguous elems
        if (tid < 252) {
            #pragma unroll
            for (int j = 0; j < 4; ++j) lv[j] = ld4_nt(src + tid*16 + j*4);
        }
    };
    auto stage_write = [&](int n) {
        if (tid < 252) {
            #pragma unroll
            for (int j = 0; j < 4; ++j)
                #pragma unroll
                for (int l = 0; l < 4; ++l) {
                    int e = tid*16 + j*4 + l;
                    int p = e/63, c = e - 63*p;
                    xs[(32 + c)*LD + p] = lv[j][l];
                }
        }
        const T* ein = ei + n*32;
        #pragma unroll
        for (int k = 0; k < 8; ++k) {
            int e = k*256 + tid;
            int row = e >> 6, p = e & 63;
            xs[row*LD + p] = (float)ein[row];
        }
    };

    stage_load(g*4);
    stage_write(g*4);
    __syncthreads();

    #pragma unroll 1
    for (int nn = 0; nn < 4; ++nn) {
        int n = g*4 + nn;

        // ---- L1: rows 0..95 -> acc -> (barrier) -> rows 0..63
        {
            f32x4 acc[4] = {};
            if (W1P) {
                const float* W1b = W1p + (size_t)(n*64 + og*4) * 96;
                #pragma unroll 4
                for (int k0 = 0; k0 < 96; k0 += 4) {
                    f32x4 wv[4], xv[4];
                    #pragma unroll
                    for (int c = 0; c < 4; ++c) wv[c] = ld4(W1b + (size_t)c*96 + k0);
                    #pragma unroll
                    for (int j = 0; j < 4; ++j) xv[j] = *(const f32x4*)&xs[(k0 + j)*LD + pg*4];
                    #pragma unroll
                    for (int c = 0; c < 4; ++c)
                        #pragma unroll
                        for (int j = 0; j < 4; ++j)
                            acc[c] += xv[j] * wv[c][j];
                }
            } else {
                const T* W1b = Wf1 + (size_t)(n*64 + og*4) * 95;
                #pragma unroll 4
                for (int kk = 0; kk < 23; ++kk) {
                    int k0 = kk*4;
                    float wv[4][4]; f32x4 xv[4];
                    #pragma unroll
                    for (int c = 0; c < 4; ++c) {
                        const T* wr = W1b + (size_t)c*95 + k0;
                        #pragma unroll
                        for (int j = 0; j < 4; ++j) wv[c][j] = (float)wr[j];
                    }
                    #pragma unroll
                    for (int j = 0; j < 4; ++j) xv[j] = *(const f32x4*)&xs[(k0 + j)*LD + pg*4];
                    #pragma unroll
                    for (int c = 0; c < 4; ++c)
                        #pragma unroll
                        for (int j = 0; j < 4; ++j)
                            acc[c] += xv[j] * wv[c][j];
                }
                { // tail k = 92..94
                    f32x4 xt[3];
                    #pragma unroll
                    for (int j = 0; j < 3; ++j) xt[j] = *(const f32x4*)&xs[(92 + j)*LD + pg*4];
                    #pragma unroll
                    for (int c = 0; c < 4; ++c) {
                        const T* wr = W1b + (size_t)c*95;
                        #pragma unroll
                        for (int j = 0; j < 3; ++j)
                            acc[c] += xt[j] * (float)wr[92 + j];
                    }
                }
            }
            __syncthreads();
            #pragma unroll
            for (int c = 0; c < 4; ++c) {
                float bb = (float)bf1[n*64 + og*4 + c];
                f32x4 hv;
                #pragma unroll
                for (int r = 0; r < 4; ++r) hv[r] = fmaxf(acc[c][r] + bb, 0.f);
                *(f32x4*)&xs[(og*4 + c)*LD + pg*4] = hv;
            }
            __syncthreads();
        }

        // ---- L2, L3: in-place rows 0..63
        layer64_ip(Wf2 + (size_t)n*64*64, bf2 + n*64, xs, og, pg);
        layer64_ip(Wf3 + (size_t)n*64*64, bf3 + n*64, xs, og, pg);

        // ---- async stage of next node's lc (global loads now; LDS writes after L4)
        if (nn < 3) stage_load(n + 1);

        // ---- L4: rows 0..63 x W4 -> fb, weighted accumulate
        {
            f32x4 wgtv = ld4_nt(wgt + (size_t)n*NPTS + p0 + pg*4);
            const T* W4n = Wf4 + (size_t)n*256*64;
            const T* b4n = bf4 + n*256;
            #pragma unroll 1
            for (int mt = 0; mt < 4; ++mt) {
                f32x4 acc[4] = {};
                #pragma unroll 4
                for (int k0 = 0; k0 < 64; k0 += 4) {
                    f32x4 wv[4], xv[4];
                    #pragma unroll
                    for (int c = 0; c < 4; ++c)
                        wv[c] = ld4(W4n + (size_t)(mt*64 + og*4 + c)*64 + k0);
                    #pragma unroll
                    for (int j = 0; j < 4; ++j) xv[j] = *(const f32x4*)&xs[(k0 + j)*LD + pg*4];
                    #pragma unroll
                    for (int c = 0; c < 4; ++c)
                        #pragma unroll
                        for (int j = 0; j < 4; ++j)
                            acc[c] += xv[j] * wv[c][j];
                }
                #pragma unroll
                for (int c = 0; c < 4; ++c) {
                    float bb = (float)b4n[mt*64 + og*4 + c];
                    #pragma unroll
                    for (int r = 0; r < 4; ++r)
                        fb[mt][c][r] += fmaxf(acc[c][r] + bb, 0.f) * wgtv[r];
                }
            }
        }
        __syncthreads();                 // L4 reads done before restage clobbers
        if (nn < 3) { stage_write(n + 1); __syncthreads(); }
    }

    // ---- output: LDS transpose then coalesced XCD-local atomicAdd into slice
    float* dst = slices + (size_t)(xcd >> shift) * NPTS * 256;
    float* tbuf = xs;   // 16 rows x 260 = 16.6 KB, fits
    #pragma unroll 1
    for (int qq = 0; qq < 4; ++qq) {
        if (qq) __syncthreads();
        if ((pg >> 2) == qq) {
            #pragma unroll
            for (int mt = 0; mt < 4; ++mt)
                #pragma unroll
                for (int r = 0; r < 4; ++r) {
                    int row = (pg & 3)*4 + r;
                    f32x4 v = { fb[mt][0][r], fb[mt][1][r], fb[mt][2][r], fb[mt][3][r] };
                    *(f32x4*)&tbuf[row*260 + mt*64 + og*4] = v;
                }
        }
        __syncthreads();
        #pragma unroll
        for (int k = 0; k < 4; ++k) {
            int idx = k*1024 + tid*4;
            int row = idx >> 8, col = idx & 255;
            f32x4 v = *(const f32x4*)&tbuf[row*260 + col];
            size_t o = ((size_t)(p0 + qq*16 + row))*256 + col;
            #pragma unroll
            for (int j = 0; j < 4; ++j) atomicAdd(&dst[o + j], v[j]);
        }
    }
}

// f_blend = sum of slices
template<int WANT>
__global__ __launch_bounds__(256) void k_reduce(
    const float* __restrict__ slices, float* __restrict__ fbl,
    int nslice, const int* __restrict__ flag)
{
    if (*flag != WANT) return;
    size_t t = (size_t)(blockIdx.x*256 + threadIdx.x) * 4;   // 131072 vec4s
    f32x4 s = {};
    for (int gg = 0; gg < nslice; ++gg)
        s += __builtin_nontemporal_load((const f32x4*)&slices[(size_t)gg*NPTS*256 + t]);
    *(f32x4*)&fbl[t] = s;
}

__global__ __launch_bounds__(256) void k_zero_fb(float* __restrict__ fb)
{
    fb[(size_t)blockIdx.x*256 + threadIdx.x] = 0.f;
}

// ---------- Nerf head (verified, unchanged) ----------
template<typename T, int WANT>
__global__ __launch_bounds__(256) void k_head_t(
    const float* __restrict__ f_blend,
    const T* __restrict__ Wc1, const T* __restrict__ bc1,
    const T* __restrict__ Wc2, const T* __restrict__ bc2,
    const T* __restrict__ Wd1, const T* __restrict__ bd1,
    T* __restrict__ out_c, T* __restrict__ out_d,
    const int* __restrict__ flag)
{
    if (*flag != WANT) return;
    int t = blockIdx.x * 256 + threadIdx.x;
    int p = t >> 6, j = t & 63;
    const float* fb = f_blend + (size_t)p * 256;

    float a = (float)bc1[j];
    #pragma unroll 8
    for (int c = 0; c < 256; ++c)
        a += fb[c] * (float)Wc1[c*64 + j];
    float nc = fmaxf(a, 0.f);

    float s0 = nc * (float)Wc2[j*3 + 0];
    float s1 = nc * (float)Wc2[j*3 + 1];
    float s2 = nc * (float)Wc2[j*3 + 2];
    float sd = 0.f;
    #pragma unroll
    for (int u = 0; u < 4; ++u) {
        int c = j*4 + u;
        sd += fb[c] * (float)Wd1[c];
    }
    #pragma unroll
    for (int off = 32; off > 0; off >>= 1) {
        s0 += __shfl_down(s0, off);
        s1 += __shfl_down(s1, off);
        s2 += __shfl_down(s2, off);
        sd += __shfl_down(sd, off);
    }
    if (j == 0) {
        out_c[p*3 + 0] = (T)(s0 + (float)bc2[0]);
        out_c[p*3 + 1] = (T)(s1 + (float)bc2[1]);
        out_c[p*3 + 2] = (T)(s2 + (float)bc2[2]);
        out_d[p]       = (T)fmaxf(sd + (float)bd1[0], 0.f);
    }
}

extern "C" void kernel_launch(void* const* d_in, const int* in_sizes, int n_in,
                              void* d_out, int out_size, void* d_ws, size_t ws_size,
                              hipStream_t stream)
{
    const size_t SLICE_BYTES = (size_t)NPTS * 256 * 4;       // 2.10 MB
    const size_t W1P_BYTES   = (size_t)128 * 64 * 96 * 4;    // 3.15 MB

    char* wsp = (char*)d_ws;
    auto alloc = [&](size_t bytes) { char* r = wsp; wsp += (bytes + 255) & ~(size_t)255; return r; };
    float* f_blend = (float*)alloc(SLICE_BYTES);
    float* wgt     = (float*)alloc((size_t)128 * NPTS * 4);
    int*   flag    = (int*)  alloc(256);

    float* W1p = nullptr;
    bool use_w1p = ((size_t)(wsp - (char*)d_ws) + W1P_BYTES) <= ws_size;
    if (use_w1p) W1p = (float*)alloc(W1P_BYTES);

    // XCD-local partial slices: 8 preferred, cascade 4/2/1, fallback = f_blend direct
    int nslice = 0;
    float* slices = nullptr;
    for (int cand = 8; cand >= 1; cand >>= 1) {
        if ((size_t)(wsp - (char*)d_ws) + (size_t)cand*SLICE_BYTES <= ws_size) {
            slices = (float*)alloc((size_t)cand*SLICE_BYTES);
            nslice = cand;
            break;
        }
    }
    bool skip_reduce = false;
    if (nslice == 0) { slices = f_blend; nslice = 1; skip_reduce = true; }
    int shift = (nslice == 8) ? 0 : (nslice == 4) ? 1 : (nslice == 2) ? 2 : 3;

    hipLaunchKernelGGL(k_sniff, dim3(1), dim3(256), 0, stream, d_in[0], flag);
    // zero the atomic target region (slices, or f_blend in fallback)
    hipLaunchKernelGGL(k_zero_fb, dim3(nslice * 2048), dim3(256), 0, stream, slices);

    #define LAUNCH_ALL(T, WANT)                                                         \
    {                                                                                   \
        const T* poses = (const T*)d_in[0];                                             \
        const T* t_ped = (const T*)d_in[1];                                             \
        const T* w     = (const T*)d_in[2];                                             \
        const T* wpts  = (const T*)d_in[3];                                             \
        const T* nodes = (const T*)d_in[4];                                             \
        const T* lc    = (const T*)d_in[5];                                             \
        const T* Wec1  = (const T*)d_in[6];  const T* bec1 = (const T*)d_in[7];         \
        const T* Wec21 = (const T*)d_in[8];  const T* bec21= (const T*)d_in[9];         \
        const T* Wec22 = (const T*)d_in[10]; const T* bec22= (const T*)d_in[11];        \
        const T* Wdc1  = (const T*)d_in[12]; const T* bdc1 = (const T*)d_in[13];        \
        const T* Wdc21 = (const T*)d_in[14]; const T* bdc21= (const T*)d_in[15];        \
        const T* Wdc22 = (const T*)d_in[16]; const T* bdc22= (const T*)d_in[17];        \
        const T* Wf1   = (const T*)d_in[18]; const T* bf1  = (const T*)d_in[19];        \
        const T* Wf2   = (const T*)d_in[20]; const T* bf2  = (const T*)d_in[21];        \
        const T* Wf3   = (const T*)d_in[22]; const T* bf3  = (const T*)d_in[23];        \
        const T* Wf4   = (const T*)d_in[24]; const T* bf4  = (const T*)d_in[25];        \
        const T* Wc1   = (const T*)d_in[26]; const T* bc1  = (const T*)d_in[27];        \
        const T* Wc2   = (const T*)d_in[28]; const T* bc2  = (const T*)d_in[29];        \
        const T* Wd1   = (const T*)d_in[30]; const T* bd1  = (const T*)d_in[31];        \
        T* out = (T*)d_out;                                                             \
        T* out_c      = out;                                                            \
        T* out_d      = out + 6144;                                                     \
        T* out_ei     = out + 8192;                                                     \
        T* out_delta  = out + 12288;                                                    \
        T* out_mean   = out + 12672;                                                    \
        T* out_logvar = out + 13696;                                                    \
        hipLaunchKernelGGL((k_encdec_t<T, WANT>), dim3(128), dim3(128), 0, stream,      \
            poses, t_ped, w, Wec1, bec1, Wec21, bec21, Wec22, bec22,                    \
            Wdc1, bdc1, Wdc21, bdc21, Wdc22, bdc22,                                     \
            out_ei, out_delta, out_mean, out_logvar, flag);                             \
        hipLaunchKernelGGL((k_bweights_t<T, WANT>), dim3(8), dim3(256), 0, stream,      \
            wpts, nodes, wgt, flag);                                                    \
        if (use_w1p) {                                                                  \
            hipLaunchKernelGGL((k_w1prep<T, WANT>), dim3(128), dim3(256), 0, stream,    \
                Wf1, W1p, flag);                                                        \
            hipLaunchKernelGGL((k_feat_fast<T, WANT, 1>), dim3(1024), dim3(256), 0,     \
                stream, Wf1, Wf2, Wf3, Wf4, lc, (const T*)out_ei,                       \
                bf1, bf2, bf3, bf4, wgt, W1p, shift, slices, flag);                     \
        } else {                                                                        \
            hipLaunchKernelGGL((k_feat_fast<T, WANT, 0>), dim3(1024), dim3(256), 0,     \
                stream, Wf1, Wf2, Wf3, Wf4, lc, (const T*)out_ei,                       \
                bf1, bf2, bf3, bf4, wgt, W1p, shift, slices, flag);                     \
        }                                                                               \
        if (!skip_reduce)                                                               \
            hipLaunchKernelGGL((k_reduce<WANT>), dim3(512), dim3(256), 0, stream,       \
                slices, f_blend, nslice, flag);                                         \
        hipLaunchKernelGGL((k_head_t<T, WANT>), dim3(512), dim3(256), 0, stream,        \
            f_blend, Wc1, bc1, Wc2, bc2, Wd1, bd1, out_c, out_d, flag);                 \
    }

    LAUNCH_ALL(bf16, 1)
    LAUNCH_ALL(float, 0)
    #undef LAUNCH_ALL
}

// Round 6
// 727.816 us; speedup vs baseline: 1.0829x; 1.0829x over previous
//
#include <hip/hip_runtime.h>

typedef __bf16 bf16;
typedef __bf16 bf16x4 __attribute__((ext_vector_type(4)));
typedef float  f32x4  __attribute__((ext_vector_type(4)));
typedef unsigned short u16x4 __attribute__((ext_vector_type(4)));

#define NPTS 2048
#define LD 68          // LDS row stride (64 pts + 4 pad)
// s_getreg imm: id=20 (HW_REG_XCC_ID), offset=0, width=32 -> 20 | (31<<11)
#define XCC_ID_IMM 63508

// ---------- dtype sniff ----------
__global__ __launch_bounds__(256) void k_sniff(const void* poses_raw, int* flag)
{
    __shared__ int cnt;
    if (threadIdx.x == 0) cnt = 0;
    __syncthreads();
    const bf16* pb = (const bf16*)poses_raw;
    int local = 0;
    for (int i = threadIdx.x; i < 9216; i += 256) {
        float v = (float)pb[i];
        if (!(v >= -2.0f && v <= 2.0f)) local++;
    }
    atomicAdd(&cnt, local);
    __syncthreads();
    if (threadIdx.x == 0) *flag = (cnt < 64) ? 1 : 0;
}

// ---------- encoder/decoder (verified, unchanged) ----------
template<typename T, int WANT>
__global__ __launch_bounds__(128) void k_encdec_t(
    const T* __restrict__ poses, const T* __restrict__ t_ped, const T* __restrict__ w,
    const T* __restrict__ Wec1, const T* __restrict__ bec1,
    const T* __restrict__ Wec21, const T* __restrict__ bec21,
    const T* __restrict__ Wec22, const T* __restrict__ bec22,
    const T* __restrict__ Wdc1, const T* __restrict__ bdc1,
    const T* __restrict__ Wdc21, const T* __restrict__ bdc21,
    const T* __restrict__ Wdc22, const T* __restrict__ bdc22,
    T* __restrict__ out_ei, T* __restrict__ out_delta,
    T* __restrict__ out_mean, T* __restrict__ out_logvar,
    const int* __restrict__ flag)
{
    if (*flag != WANT) return;
    int n = blockIdx.x, tid = threadIdx.x;
    __shared__ float sin_[88], zbuf[8], net1[64], din[80], net2[64];
    if (tid < 72)      sin_[tid] = (float)w[n*24 + tid/3] * (float)poses[n*72 + tid];
    else if (tid < 88) sin_[tid] = (float)t_ped[tid - 72];
    __syncthreads();
    if (tid < 64) {
        float a = (float)bec1[n*64 + tid];
        const T* wr = Wec1 + (size_t)(n*64 + tid) * 88;
        for (int c = 0; c < 88; ++c) a += (float)wr[c] * sin_[c];
        net1[tid] = fmaxf(a, 0.f);
    }
    __syncthreads();
    if (tid < 8) {
        float a = (float)bec21[n*8 + tid];
        const T* wr = Wec21 + (size_t)(n*8 + tid) * 64;
        for (int c = 0; c < 64; ++c) a += (float)wr[c] * net1[c];
        out_mean[n*8 + tid] = (T)a;
        zbuf[tid] = a;
    } else if (tid < 16) {
        int o = tid - 8;
        float a = (float)bec22[n*8 + o];
        const T* wr = Wec22 + (size_t)(n*8 + o) * 64;
        for (int c = 0; c < 64; ++c) a += (float)wr[c] * net1[c];
        out_logvar[n*8 + o] = (T)a;
    }
    __syncthreads();
    if (tid < 72)      din[tid] = sin_[tid];
    else if (tid < 80) din[tid] = zbuf[tid - 72];
    __syncthreads();
    if (tid < 64) {
        float a = (float)bdc1[n*64 + tid];
        const T* wr = Wdc1 + (size_t)(n*64 + tid) * 80;
        for (int c = 0; c < 80; ++c) a += (float)wr[c] * din[c];
        net2[tid] = fmaxf(a, 0.f);
    }
    __syncthreads();
    if (tid < 32) {
        float a = (float)bdc21[n*32 + tid];
        const T* wr = Wdc21 + (size_t)(n*32 + tid) * 64;
        for (int c = 0; c < 64; ++c) a += (float)wr[c] * net2[c];
        out_ei[n*32 + tid] = (T)a;
    } else if (tid < 35) {
        int o = tid - 32;
        float a = (float)bdc22[n*3 + o];
        const T* wr = Wdc22 + (size_t)(n*3 + o) * 64;
        for (int c = 0; c < 64; ++c) a += (float)wr[c] * net2[c];
        out_delta[n*3 + o] = (T)a;
    }
}

// ---------- per-point inverse denominator (replaces wgt buffer) ----------
template<typename T, int WANT>
__global__ __launch_bounds__(256) void k_denom(
    const T* __restrict__ wpts, const T* __restrict__ nodes,
    float* __restrict__ inv, const int* __restrict__ flag)
{
    if (*flag != WANT) return;
    int v = blockIdx.x * 256 + threadIdx.x;
    float px = (float)wpts[v*3+0], py = (float)wpts[v*3+1], pz = (float)wpts[v*3+2];
    float denom = 0.f;
    for (int n = 0; n < 128; ++n) {
        float dx = px - (float)nodes[n*3+0];
        float dy = py - (float)nodes[n*3+1];
        float dz = pz - (float)nodes[n*3+2];
        float d2 = dx*dx + dy*dy + dz*dz;
        float influ = expf(-d2 * (1.0f/0.18f)) - 0.01f;
        denom += fmaxf(influ, 0.f) + 1e-7f;
    }
    inv[v] = 1.f / denom;
}

// ---------- helpers ----------
__device__ __forceinline__ f32x4 ld4(const float* p) { return *(const f32x4*)p; }
__device__ __forceinline__ f32x4 ld4(const bf16* p)
{
    bf16x4 v = *(const bf16x4*)p;
    f32x4 r;
    #pragma unroll
    for (int j = 0; j < 4; ++j) r[j] = (float)v[j];
    return r;
}
__device__ __forceinline__ f32x4 ld4_nt(const float* p)
{
    return __builtin_nontemporal_load((const f32x4*)p);
}
__device__ __forceinline__ f32x4 ld4_nt(const bf16* p)
{
    u16x4 u = __builtin_nontemporal_load((const u16x4*)p);
    f32x4 r;
    #pragma unroll
    for (int j = 0; j < 4; ++j) {
        unsigned int bits = ((unsigned int)u[j]) << 16;
        r[j] = __uint_as_float(bits);
    }
    return r;
}

// W1 -> padded fp32 [128][64][96], col 95 zeroed
template<typename T, int WANT>
__global__ __launch_bounds__(256) void k_w1prep(
    const T* __restrict__ Wf1, float* __restrict__ W1p, const int* __restrict__ flag)
{
    if (*flag != WANT) return;
    int n = blockIdx.x, tid = threadIdx.x;
    for (int e = tid; e < 6144; e += 256) {
        int oc = e / 96, k = e - oc*96;
        float v = (k < 95) ? (float)Wf1[(size_t)n*6080 + oc*95 + k] : 0.f;
        W1p[(size_t)n*6144 + e] = v;
    }
}

// 64->64 layer (round-3 proven): W from global, x k-major LDS, ping-pong out
template<typename T>
__device__ __forceinline__ void layer64g(
    const T* __restrict__ W, const T* __restrict__ b,
    const float* __restrict__ hin, float* __restrict__ hout, int og, int pg)
{
    f32x4 acc[4] = {};
    #pragma unroll 4
    for (int k0 = 0; k0 < 64; k0 += 4) {
        f32x4 wv[4], xv[4];
        #pragma unroll
        for (int c = 0; c < 4; ++c) wv[c] = ld4(W + (size_t)(og*4 + c)*64 + k0);
        #pragma unroll
        for (int j = 0; j < 4; ++j) xv[j] = *(const f32x4*)&hin[(k0 + j)*LD + pg*4];
        #pragma unroll
        for (int c = 0; c < 4; ++c)
            #pragma unroll
            for (int j = 0; j < 4; ++j)
                acc[c] += xv[j] * wv[c][j];
    }
    #pragma unroll
    for (int c = 0; c < 4; ++c) {
        float bb = (float)b[og*4 + c];
        f32x4 hv;
        #pragma unroll
        for (int r = 0; r < 4; ++r) hv[r] = fmaxf(acc[c][r] + bb, 0.f);
        *(f32x4*)&hout[(og*4 + c)*LD + pg*4] = hv;
    }
}

// ---------- feature field v6: P=64, 32 groups x 4 nodes (grid 1024, 3 blk/CU),
//            round-3 compute body, real-XCD-exclusive atomic slices ----------
template<typename T, int WANT, int W1P>
__global__ __launch_bounds__(256, 3) void k_feat_fast(
    const T* __restrict__ Wf1, const T* __restrict__ Wf2,
    const T* __restrict__ Wf3, const T* __restrict__ Wf4,
    const T* __restrict__ lc, const T* __restrict__ ei,
    const T* __restrict__ bf1, const T* __restrict__ bf2,
    const T* __restrict__ bf3, const T* __restrict__ bf4,
    const T* __restrict__ wpts, const T* __restrict__ nodes,
    const float* __restrict__ inv, const float* __restrict__ W1p,
    int shift, float* __restrict__ slices,
    const int* __restrict__ flag)
{
    if (*flag != WANT) return;
    // read-locality mapping (bid%8 ~ XCD heuristic, proven for reads in r3)
    int bid = blockIdx.x;                // 0..1023
    int xcdg = bid & 7;
    int i    = bid >> 3;                 // 0..127
    int g     = 4*xcdg + (i >> 5);       // 0..31  (4 nodes each)
    int ptile = i & 31;                  // 0..31  (64 pts each)
    int p0  = ptile * 64;
    int tid = threadIdx.x;
    int og = tid >> 4;                   // 16 x 4 out-channels
    int pg = tid & 15;                   // 16 x 4 points

    // REAL XCD for atomic-exclusive slice (hwreg 20; masked -> always safe)
    int xcdr = (__builtin_amdgcn_s_getreg(XCC_ID_IMM) & 7) >> shift;

    __shared__ __attribute__((aligned(16))) float smem[(96 + 64) * LD];  // 43.5 KB
    float* xs = smem;
    float* hA = smem + 96*LD;

    if (tid < 64) xs[95*LD + tid] = 0.f;   // K=96 zero row (W1P path)

    // per-thread point data, fixed across nodes
    float px[4], py[4], pz[4], pinv[4];
    #pragma unroll
    for (int r = 0; r < 4; ++r) {
        int p = p0 + pg*4 + r;
        px[r] = (float)wpts[p*3+0];
        py[r] = (float)wpts[p*3+1];
        pz[r] = (float)wpts[p*3+2];
        pinv[r] = inv[p];
    }

    f32x4 fb[4][4];
    #pragma unroll
    for (int a = 0; a < 4; ++a)
        #pragma unroll
        for (int c = 0; c < 4; ++c) fb[a][c] = (f32x4){0.f,0.f,0.f,0.f};

    f32x4 lv[4];

    auto stage_load = [&](int n) {
        const T* src = lc + ((size_t)n*NPTS + p0) * 63;
        if (tid < 252) {
            #pragma unroll
            for (int j = 0; j < 4; ++j) lv[j] = ld4_nt(src + tid*16 + j*4);
        }
    };
    auto stage_write = [&](int n) {
        if (tid < 252) {
            #pragma unroll
            for (int j = 0; j < 4; ++j)
                #pragma unroll
                for (int l = 0; l < 4; ++l) {
                    int e = tid*16 + j*4 + l;
                    int p = e/63, c = e - 63*p;
                    xs[(32 + c)*LD + p] = lv[j][l];
                }
        }
        const T* ein = ei + n*32;
        #pragma unroll
        for (int k = 0; k < 8; ++k) {
            int e = k*256 + tid;
            int row = e >> 6, p = e & 63;
            xs[row*LD + p] = (float)ein[row];
        }
    };

    stage_load(g*4);
    stage_write(g*4);
    __syncthreads();

    #pragma unroll 1
    for (int nn = 0; nn < 4; ++nn) {
        int n = g*4 + nn;

        // ---- L1: xs rows 0..95 -> hA
        {
            f32x4 acc[4] = {};
            if (W1P) {
                const float* W1b = W1p + (size_t)(n*64 + og*4) * 96;
                #pragma unroll 4
                for (int k0 = 0; k0 < 96; k0 += 4) {
                    f32x4 wv[4], xv[4];
                    #pragma unroll
                    for (int c = 0; c < 4; ++c) wv[c] = ld4(W1b + (size_t)c*96 + k0);
                    #pragma unroll
                    for (int j = 0; j < 4; ++j) xv[j] = *(const f32x4*)&xs[(k0 + j)*LD + pg*4];
                    #pragma unroll
                    for (int c = 0; c < 4; ++c)
                        #pragma unroll
                        for (int j = 0; j < 4; ++j)
                            acc[c] += xv[j] * wv[c][j];
                }
            } else {
                const T* W1b = Wf1 + (size_t)(n*64 + og*4) * 95;
                #pragma unroll 4
                for (int kk = 0; kk < 23; ++kk) {
                    int k0 = kk*4;
                    float wv[4][4]; f32x4 xv[4];
                    #pragma unroll
                    for (int c = 0; c < 4; ++c) {
                        const T* wr = W1b + (size_t)c*95 + k0;
                        #pragma unroll
                        for (int j = 0; j < 4; ++j) wv[c][j] = (float)wr[j];
                    }
                    #pragma unroll
                    for (int j = 0; j < 4; ++j) xv[j] = *(const f32x4*)&xs[(k0 + j)*LD + pg*4];
                    #pragma unroll
                    for (int c = 0; c < 4; ++c)
                        #pragma unroll
                        for (int j = 0; j < 4; ++j)
                            acc[c] += xv[j] * wv[c][j];
                }
                {
                    f32x4 xt[3];
                    #pragma unroll
                    for (int j = 0; j < 3; ++j) xt[j] = *(const f32x4*)&xs[(92 + j)*LD + pg*4];
                    #pragma unroll
                    for (int c = 0; c < 4; ++c) {
                        const T* wr = W1b + (size_t)c*95;
                        #pragma unroll
                        for (int j = 0; j < 3; ++j)
                            acc[c] += xt[j] * (float)wr[92 + j];
                    }
                }
            }
            #pragma unroll
            for (int c = 0; c < 4; ++c) {
                float bb = (float)bf1[n*64 + og*4 + c];
                f32x4 hv;
                #pragma unroll
                for (int r = 0; r < 4; ++r) hv[r] = fmaxf(acc[c][r] + bb, 0.f);
                *(f32x4*)&hA[(og*4 + c)*LD + pg*4] = hv;
            }
        }
        __syncthreads();

        // ---- L2: hA -> xs rows 0..63
        layer64g(Wf2 + (size_t)n*64*64, bf2 + n*64, hA, xs, og, pg);
        __syncthreads();

        // ---- L3: xs -> hA
        layer64g(Wf3 + (size_t)n*64*64, bf3 + n*64, xs, hA, og, pg);
        __syncthreads();

        // ---- async stage of next node's lc
        if (nn < 3) stage_load(n + 1);

        // ---- L4: hA x W4 -> fb, weighted accumulate (wgt computed inline)
        {
            float nx = (float)nodes[n*3+0], ny = (float)nodes[n*3+1], nz = (float)nodes[n*3+2];
            f32x4 wgtv;
            #pragma unroll
            for (int r = 0; r < 4; ++r) {
                float dx = px[r]-nx, dy = py[r]-ny, dz = pz[r]-nz;
                float d2 = dx*dx + dy*dy + dz*dz;
                float influ = expf(-d2 * (1.0f/0.18f)) - 0.01f;
                wgtv[r] = (influ >= 0.f) ? (fmaxf(influ, 0.f) + 1e-7f) * pinv[r] : 0.f;
            }
            const T* W4n = Wf4 + (size_t)n*256*64;
            const T* b4n = bf4 + n*256;
            #pragma unroll 1
            for (int mt = 0; mt < 4; ++mt) {
                f32x4 acc[4] = {};
                #pragma unroll 4
                for (int k0 = 0; k0 < 64; k0 += 4) {
                    f32x4 wv[4], xv[4];
                    #pragma unroll
                    for (int c = 0; c < 4; ++c)
                        wv[c] = ld4(W4n + (size_t)(mt*64 + og*4 + c)*64 + k0);
                    #pragma unroll
                    for (int j = 0; j < 4; ++j) xv[j] = *(const f32x4*)&hA[(k0 + j)*LD + pg*4];
                    #pragma unroll
                    for (int c = 0; c < 4; ++c)
                        #pragma unroll
                        for (int j = 0; j < 4; ++j)
                            acc[c] += xv[j] * wv[c][j];
                }
                #pragma unroll
                for (int c = 0; c < 4; ++c) {
                    float bb = (float)b4n[mt*64 + og*4 + c];
                    #pragma unroll
                    for (int r = 0; r < 4; ++r)
                        fb[mt][c][r] += fmaxf(acc[c][r] + bb, 0.f) * wgtv[r];
                }
            }
        }
        __syncthreads();                 // L4 reads done before restage
        if (nn < 3) { stage_write(n + 1); __syncthreads(); }
    }

    // ---- output: LDS transpose, coalesced atomicAdd into REAL-XCD-exclusive slice
    float* dst = slices + (size_t)xcdr * NPTS * 256;
    float* tbuf = smem;   // 16 rows x 260 floats, fits
    #pragma unroll 1
    for (int qq = 0; qq < 4; ++qq) {
        if (qq) __syncthreads();
        if ((pg >> 2) == qq) {
            #pragma unroll
            for (int mt = 0; mt < 4; ++mt)
                #pragma unroll
                for (int r = 0; r < 4; ++r) {
                    int row = (pg & 3)*4 + r;
                    f32x4 v = { fb[mt][0][r], fb[mt][1][r], fb[mt][2][r], fb[mt][3][r] };
                    *(f32x4*)&tbuf[row*260 + mt*64 + og*4] = v;
                }
        }
        __syncthreads();
        #pragma unroll
        for (int k = 0; k < 4; ++k) {
            int idx = k*1024 + tid*4;
            int row = idx >> 8, col = idx & 255;
            f32x4 v = *(const f32x4*)&tbuf[row*260 + col];
            size_t o = ((size_t)(p0 + qq*16 + row))*256 + col;
            #pragma unroll
            for (int j = 0; j < 4; ++j) atomicAdd(&dst[o + j], v[j]);
        }
    }
}

// in-place: slices[0] += slices[1..n-1]
template<int WANT>
__global__ __launch_bounds__(256) void k_reduce(
    float* __restrict__ slices, int nslice, const int* __restrict__ flag)
{
    if (*flag != WANT) return;
    size_t t = (size_t)(blockIdx.x*256 + threadIdx.x) * 4;
    f32x4 s = *(const f32x4*)&slices[t];
    for (int gg = 1; gg < nslice; ++gg)
        s += __builtin_nontemporal_load((const f32x4*)&slices[(size_t)gg*NPTS*256 + t]);
    *(f32x4*)&slices[t] = s;
}

__global__ __launch_bounds__(256) void k_zero_fb(float* __restrict__ fb)
{
    fb[(size_t)blockIdx.x*256 + threadIdx.x] = 0.f;
}

// ---------- Nerf head (verified, unchanged; f_blend := slices[0]) ----------
template<typename T, int WANT>
__global__ __launch_bounds__(256) void k_head_t(
    const float* __restrict__ f_blend,
    const T* __restrict__ Wc1, const T* __restrict__ bc1,
    const T* __restrict__ Wc2, const T* __restrict__ bc2,
    const T* __restrict__ Wd1, const T* __restrict__ bd1,
    T* __restrict__ out_c, T* __restrict__ out_d,
    const int* __restrict__ flag)
{
    if (*flag != WANT) return;
    int t = blockIdx.x * 256 + threadIdx.x;
    int p = t >> 6, j = t & 63;
    const float* fb = f_blend + (size_t)p * 256;

    float a = (float)bc1[j];
    #pragma unroll 8
    for (int c = 0; c < 256; ++c)
        a += fb[c] * (float)Wc1[c*64 + j];
    float nc = fmaxf(a, 0.f);

    float s0 = nc * (float)Wc2[j*3 + 0];
    float s1 = nc * (float)Wc2[j*3 + 1];
    float s2 = nc * (float)Wc2[j*3 + 2];
    float sd = 0.f;
    #pragma unroll
    for (int u = 0; u < 4; ++u) {
        int c = j*4 + u;
        sd += fb[c] * (float)Wd1[c];
    }
    #pragma unroll
    for (int off = 32; off > 0; off >>= 1) {
        s0 += __shfl_down(s0, off);
        s1 += __shfl_down(s1, off);
        s2 += __shfl_down(s2, off);
        sd += __shfl_down(sd, off);
    }
    if (j == 0) {
        out_c[p*3 + 0] = (T)(s0 + (float)bc2[0]);
        out_c[p*3 + 1] = (T)(s1 + (float)bc2[1]);
        out_c[p*3 + 2] = (T)(s2 + (float)bc2[2]);
        out_d[p]       = (T)fmaxf(sd + (float)bd1[0], 0.f);
    }
}

extern "C" void kernel_launch(void* const* d_in, const int* in_sizes, int n_in,
                              void* d_out, int out_size, void* d_ws, size_t ws_size,
                              hipStream_t stream)
{
    const size_t SLICE_BYTES = (size_t)NPTS * 256 * 4;       // 2.10 MB
    const size_t W1P_BYTES   = (size_t)128 * 64 * 96 * 4;    // 3.15 MB
    const size_t INV_BYTES   = (size_t)NPTS * 4;             // 8 KB

    // decide layout (all sizes padded to 256 in alloc; base pad covered by +4KB slack)
    size_t base = ((INV_BYTES + 255) & ~(size_t)255) + 256 + 4096;
    bool use_w1p = false; int nslice = 1;
    if      (base + W1P_BYTES + 8*SLICE_BYTES <= ws_size) { use_w1p = true;  nslice = 8; }
    else if (base + 8*SLICE_BYTES <= ws_size)             { use_w1p = false; nslice = 8; }
    else if (base + W1P_BYTES + 4*SLICE_BYTES <= ws_size) { use_w1p = true;  nslice = 4; }
    else if (base + 4*SLICE_BYTES <= ws_size)             { use_w1p = false; nslice = 4; }
    else if (base + 2*SLICE_BYTES <= ws_size)             { use_w1p = false; nslice = 2; }
    else                                                  { use_w1p = false; nslice = 1; }
    int shift = (nslice == 8) ? 0 : (nslice == 4) ? 1 : (nslice == 2) ? 2 : 3;

    char* wsp = (char*)d_ws;
    auto alloc = [&](size_t bytes) { char* r = wsp; wsp += (bytes + 255) & ~(size_t)255; return r; };
    float* inv  = (float*)alloc(INV_BYTES);
    int*   flag = (int*)  alloc(256);
    float* W1p  = use_w1p ? (float*)alloc(W1P_BYTES) : nullptr;
    float* slices = (float*)alloc((size_t)nslice * SLICE_BYTES);
    float* f_blend = slices;   // after k_reduce, slice 0 holds the sum

    hipLaunchKernelGGL(k_sniff, dim3(1), dim3(256), 0, stream, d_in[0], flag);
    hipLaunchKernelGGL(k_zero_fb, dim3(nslice * 2048), dim3(256), 0, stream, slices);

    #define LAUNCH_ALL(T, WANT)                                                         \
    {                                                                                   \
        const T* poses = (const T*)d_in[0];                                             \
        const T* t_ped = (const T*)d_in[1];                                             \
        const T* w     = (const T*)d_in[2];                                             \
        const T* wpts  = (const T*)d_in[3];                                             \
        const T* nodes = (const T*)d_in[4];                                             \
        const T* lc    = (const T*)d_in[5];                                             \
        const T* Wec1  = (const T*)d_in[6];  const T* bec1 = (const T*)d_in[7];         \
        const T* Wec21 = (const T*)d_in[8];  const T* bec21= (const T*)d_in[9];         \
        const T* Wec22 = (const T*)d_in[10]; const T* bec22= (const T*)d_in[11];        \
        const T* Wdc1  = (const T*)d_in[12]; const T* bdc1 = (const T*)d_in[13];        \
        const T* Wdc21 = (const T*)d_in[14]; const T* bdc21= (const T*)d_in[15];        \
        const T* Wdc22 = (const T*)d_in[16]; const T* bdc22= (const T*)d_in[17];        \
        const T* Wf1   = (const T*)d_in[18]; const T* bf1  = (const T*)d_in[19];        \
        const T* Wf2   = (const T*)d_in[20]; const T* bf2  = (const T*)d_in[21];        \
        const T* Wf3   = (const T*)d_in[22]; const T* bf3  = (const T*)d_in[23];        \
        const T* Wf4   = (const T*)d_in[24]; const T* bf4  = (const T*)d_in[25];        \
        const T* Wc1   = (const T*)d_in[26]; const T* bc1  = (const T*)d_in[27];        \
        const T* Wc2   = (const T*)d_in[28]; const T* bc2  = (const T*)d_in[29];        \
        const T* Wd1   = (const T*)d_in[30]; const T* bd1  = (const T*)d_in[31];        \
        T* out = (T*)d_out;                                                             \
        T* out_c      = out;                                                            \
        T* out_d      = out + 6144;                                                     \
        T* out_ei     = out + 8192;                                                     \
        T* out_delta  = out + 12288;                                                    \
        T* out_mean   = out + 12672;                                                    \
        T* out_logvar = out + 13696;                                                    \
        hipLaunchKernelGGL((k_encdec_t<T, WANT>), dim3(128), dim3(128), 0, stream,      \
            poses, t_ped, w, Wec1, bec1, Wec21, bec21, Wec22, bec22,                    \
            Wdc1, bdc1, Wdc21, bdc21, Wdc22, bdc22,                                     \
            out_ei, out_delta, out_mean, out_logvar, flag);                             \
        hipLaunchKernelGGL((k_denom<T, WANT>), dim3(8), dim3(256), 0, stream,           \
            wpts, nodes, inv, flag);                                                    \
        if (use_w1p) {                                                                  \
            hipLaunchKernelGGL((k_w1prep<T, WANT>), dim3(128), dim3(256), 0, stream,    \
                Wf1, W1p, flag);                                                        \
            hipLaunchKernelGGL((k_feat_fast<T, WANT, 1>), dim3(1024), dim3(256), 0,     \
                stream, Wf1, Wf2, Wf3, Wf4, lc, (const T*)out_ei,                       \
                bf1, bf2, bf3, bf4, wpts, nodes, inv, W1p, shift, slices, flag);        \
        } else {                                                                        \
            hipLaunchKernelGGL((k_feat_fast<T, WANT, 0>), dim3(1024), dim3(256), 0,     \
                stream, Wf1, Wf2, Wf3, Wf4, lc, (const T*)out_ei,                       \
                bf1, bf2, bf3, bf4, wpts, nodes, inv, W1p, shift, slices, flag);        \
        }                                                                               \
        if (nslice > 1)                                                                 \
            hipLaunchKernelGGL((k_reduce<WANT>), dim3(512), dim3(256), 0, stream,       \
                slices, nslice, flag);                                                  \
        hipLaunchKernelGGL((k_head_t<T, WANT>), dim3(512), dim3(256), 0, stream,        \
            f_blend, Wc1, bc1, Wc2, bc2, Wd1, bd1, out_c, out_d, flag);                 \
    }

    LAUNCH_ALL(bf16, 1)
    LAUNCH_ALL(float, 0)
    #undef LAUNCH_ALL
}

// Round 7
// 595.669 us; speedup vs baseline: 1.3232x; 1.2218x over previous
//
#include <hip/hip_runtime.h>

typedef __bf16 bf16;
typedef __bf16 bf16x4 __attribute__((ext_vector_type(4)));
typedef float  f32x4  __attribute__((ext_vector_type(4)));
typedef unsigned short u16x4 __attribute__((ext_vector_type(4)));

#define NPTS 2048
#define LD 68          // LDS row stride (64 pts + 4 pad)

// ---------- dtype sniff ----------
__global__ __launch_bounds__(256) void k_sniff(const void* poses_raw, int* flag)
{
    __shared__ int cnt;
    if (threadIdx.x == 0) cnt = 0;
    __syncthreads();
    const bf16* pb = (const bf16*)poses_raw;
    int local = 0;
    for (int i = threadIdx.x; i < 9216; i += 256) {
        float v = (float)pb[i];
        if (!(v >= -2.0f && v <= 2.0f)) local++;
    }
    atomicAdd(&cnt, local);
    __syncthreads();
    if (threadIdx.x == 0) *flag = (cnt < 64) ? 1 : 0;
}

// ---------- encoder/decoder (verified, unchanged) ----------
template<typename T, int WANT>
__global__ __launch_bounds__(128) void k_encdec_t(
    const T* __restrict__ poses, const T* __restrict__ t_ped, const T* __restrict__ w,
    const T* __restrict__ Wec1, const T* __restrict__ bec1,
    const T* __restrict__ Wec21, const T* __restrict__ bec21,
    const T* __restrict__ Wec22, const T* __restrict__ bec22,
    const T* __restrict__ Wdc1, const T* __restrict__ bdc1,
    const T* __restrict__ Wdc21, const T* __restrict__ bdc21,
    const T* __restrict__ Wdc22, const T* __restrict__ bdc22,
    T* __restrict__ out_ei, T* __restrict__ out_delta,
    T* __restrict__ out_mean, T* __restrict__ out_logvar,
    const int* __restrict__ flag)
{
    if (*flag != WANT) return;
    int n = blockIdx.x, tid = threadIdx.x;
    __shared__ float sin_[88], zbuf[8], net1[64], din[80], net2[64];
    if (tid < 72)      sin_[tid] = (float)w[n*24 + tid/3] * (float)poses[n*72 + tid];
    else if (tid < 88) sin_[tid] = (float)t_ped[tid - 72];
    __syncthreads();
    if (tid < 64) {
        float a = (float)bec1[n*64 + tid];
        const T* wr = Wec1 + (size_t)(n*64 + tid) * 88;
        for (int c = 0; c < 88; ++c) a += (float)wr[c] * sin_[c];
        net1[tid] = fmaxf(a, 0.f);
    }
    __syncthreads();
    if (tid < 8) {
        float a = (float)bec21[n*8 + tid];
        const T* wr = Wec21 + (size_t)(n*8 + tid) * 64;
        for (int c = 0; c < 64; ++c) a += (float)wr[c] * net1[c];
        out_mean[n*8 + tid] = (T)a;
        zbuf[tid] = a;
    } else if (tid < 16) {
        int o = tid - 8;
        float a = (float)bec22[n*8 + o];
        const T* wr = Wec22 + (size_t)(n*8 + o) * 64;
        for (int c = 0; c < 64; ++c) a += (float)wr[c] * net1[c];
        out_logvar[n*8 + o] = (T)a;
    }
    __syncthreads();
    if (tid < 72)      din[tid] = sin_[tid];
    else if (tid < 80) din[tid] = zbuf[tid - 72];
    __syncthreads();
    if (tid < 64) {
        float a = (float)bdc1[n*64 + tid];
        const T* wr = Wdc1 + (size_t)(n*64 + tid) * 80;
        for (int c = 0; c < 80; ++c) a += (float)wr[c] * din[c];
        net2[tid] = fmaxf(a, 0.f);
    }
    __syncthreads();
    if (tid < 32) {
        float a = (float)bdc21[n*32 + tid];
        const T* wr = Wdc21 + (size_t)(n*32 + tid) * 64;
        for (int c = 0; c < 64; ++c) a += (float)wr[c] * net2[c];
        out_ei[n*32 + tid] = (T)a;
    } else if (tid < 35) {
        int o = tid - 32;
        float a = (float)bdc22[n*3 + o];
        const T* wr = Wdc22 + (size_t)(n*3 + o) * 64;
        for (int c = 0; c < 64; ++c) a += (float)wr[c] * net2[c];
        out_delta[n*3 + o] = (T)a;
    }
}

// ---------- blend weights (r3-verified) ----------
template<typename T, int WANT>
__global__ __launch_bounds__(256) void k_bweights_t(
    const T* __restrict__ wpts, const T* __restrict__ nodes,
    float* __restrict__ wgt, const int* __restrict__ flag)
{
    if (*flag != WANT) return;
    int v = blockIdx.x * 256 + threadIdx.x;
    float px = (float)wpts[v*3+0], py = (float)wpts[v*3+1], pz = (float)wpts[v*3+2];
    float denom = 0.f;
    for (int n = 0; n < 128; ++n) {
        float dx = px - (float)nodes[n*3+0];
        float dy = py - (float)nodes[n*3+1];
        float dz = pz - (float)nodes[n*3+2];
        float d2 = dx*dx + dy*dy + dz*dz;
        float influ = expf(-d2 * (1.0f/0.18f)) - 0.01f;
        denom += fmaxf(influ, 0.f) + 1e-7f;
    }
    float inv = 1.f / denom;
    for (int n = 0; n < 128; ++n) {
        float dx = px - (float)nodes[n*3+0];
        float dy = py - (float)nodes[n*3+1];
        float dz = pz - (float)nodes[n*3+2];
        float d2 = dx*dx + dy*dy + dz*dz;
        float influ = expf(-d2 * (1.0f/0.18f)) - 0.01f;
        wgt[n*NPTS + v] = (influ >= 0.f) ? (fmaxf(influ, 0.f) + 1e-7f) * inv : 0.f;
    }
}

// ---------- helpers ----------
__device__ __forceinline__ f32x4 ld4(const float* p) { return *(const f32x4*)p; }
__device__ __forceinline__ f32x4 ld4(const bf16* p)
{
    bf16x4 v = *(const bf16x4*)p;
    f32x4 r;
    #pragma unroll
    for (int j = 0; j < 4; ++j) r[j] = (float)v[j];
    return r;
}
__device__ __forceinline__ f32x4 ld4_nt(const float* p)
{
    return __builtin_nontemporal_load((const f32x4*)p);
}
__device__ __forceinline__ f32x4 ld4_nt(const bf16* p)
{
    u16x4 u = __builtin_nontemporal_load((const u16x4*)p);
    f32x4 r;
    #pragma unroll
    for (int j = 0; j < 4; ++j) {
        unsigned int bits = ((unsigned int)u[j]) << 16;
        r[j] = __uint_as_float(bits);
    }
    return r;
}

// W1 -> padded fp32 [128][64][96], col 95 zeroed
template<typename T, int WANT>
__global__ __launch_bounds__(256) void k_w1prep(
    const T* __restrict__ Wf1, float* __restrict__ W1p, const int* __restrict__ flag)
{
    if (*flag != WANT) return;
    int n = blockIdx.x, tid = threadIdx.x;
    for (int e = tid; e < 6144; e += 256) {
        int oc = e / 96, k = e - oc*96;
        float v = (k < 95) ? (float)Wf1[(size_t)n*6080 + oc*95 + k] : 0.f;
        W1p[(size_t)n*6144 + e] = v;
    }
}

// ---------- feature field v7: 1024-thread blocks, grid 256 (8 groups x 32 ptiles),
//            P=64, shared single-node pipeline, store-only 8-slice output ----------
template<typename T, int WANT, int W1P>
__global__ __launch_bounds__(1024, 4) void k_feat_fast(
    const T* __restrict__ Wf1, const T* __restrict__ Wf2,
    const T* __restrict__ Wf3, const T* __restrict__ Wf4,
    const T* __restrict__ lc, const T* __restrict__ ei,
    const T* __restrict__ bf1, const T* __restrict__ bf2,
    const T* __restrict__ bf3, const T* __restrict__ bf4,
    const float* __restrict__ wgt, const float* __restrict__ W1p,
    int smask, float* __restrict__ slices,
    const int* __restrict__ flag)
{
    if (*flag != WANT) return;
    int bid = blockIdx.x;           // 0..255
    int g     = bid & 7;            // 8 groups x 16 nodes; consecutive bids -> XCD round-robin
    int ptile = bid >> 3;           // 0..31
    int p0  = ptile * 64;
    int tid = threadIdx.x;
    int og = tid >> 4;              // 0..63 (1 hidden ch; 4 out-ch in L4)
    int pg = tid & 15;              // 16 x 4 points

    __shared__ __attribute__((aligned(16))) float smem[(96 + 64) * LD];  // 43.5 KB
    float* xs = smem;               // rows 0..95 (95 = zero row for W1P K=96)
    float* hA = smem + 96*LD;       // 64 rows

    if (tid < 64) xs[95*LD + tid] = 0.f;

    f32x4 fb[4];
    #pragma unroll
    for (int c = 0; c < 4; ++c) fb[c] = (f32x4){0.f,0.f,0.f,0.f};

    f32x4 lv;

    auto stage_load = [&](int n) {
        const T* src = lc + ((size_t)n*NPTS + p0) * 63;   // 4032 contiguous elems
        if (tid < 1008) lv = ld4_nt(src + tid*4);
    };
    auto stage_write = [&](int n) {
        if (tid < 1008) {
            #pragma unroll
            for (int l = 0; l < 4; ++l) {
                int e = tid*4 + l;
                int p = e/63, c = e - 63*p;
                xs[(32 + c)*LD + p] = lv[l];
            }
        }
        const T* ein = ei + n*32;
        #pragma unroll
        for (int k = 0; k < 2; ++k) {
            int e = k*1024 + tid;
            xs[(e >> 6)*LD + (e & 63)] = (float)ein[e >> 6];
        }
    };

    stage_load(g*16);
    stage_write(g*16);
    __syncthreads();

    #pragma unroll 1
    for (int nn = 0; nn < 16; ++nn) {
        int n = g*16 + nn;

        // ---- L1: xs rows 0..95 -> hA (1 ch/thread)
        {
            f32x4 acc = {};
            if (W1P) {
                const float* W1b = W1p + (size_t)(n*64 + og) * 96;
                #pragma unroll 8
                for (int k0 = 0; k0 < 96; k0 += 4) {
                    f32x4 wv = ld4(W1b + k0);
                    #pragma unroll
                    for (int j = 0; j < 4; ++j) {
                        f32x4 xv = *(const f32x4*)&xs[(k0 + j)*LD + pg*4];
                        acc += xv * wv[j];
                    }
                }
            } else {
                const T* wr = Wf1 + (size_t)(n*64 + og) * 95;
                #pragma unroll 8
                for (int kk = 0; kk < 23; ++kk) {
                    int k0 = kk*4;
                    #pragma unroll
                    for (int j = 0; j < 4; ++j) {
                        f32x4 xv = *(const f32x4*)&xs[(k0 + j)*LD + pg*4];
                        acc += xv * (float)wr[k0 + j];
                    }
                }
                #pragma unroll
                for (int j = 92; j < 95; ++j) {
                    f32x4 xv = *(const f32x4*)&xs[j*LD + pg*4];
                    acc += xv * (float)wr[j];
                }
            }
            float bb = (float)bf1[n*64 + og];
            f32x4 hv;
            #pragma unroll
            for (int r = 0; r < 4; ++r) hv[r] = fmaxf(acc[r] + bb, 0.f);
            *(f32x4*)&hA[og*LD + pg*4] = hv;
        }
        __syncthreads();

        // ---- L2: hA -> xs rows 0..63
        {
            const T* wr = Wf2 + (size_t)(n*64 + og) * 64;
            f32x4 acc = {};
            #pragma unroll 8
            for (int k0 = 0; k0 < 64; k0 += 4) {
                f32x4 wv = ld4(wr + k0);
                #pragma unroll
                for (int j = 0; j < 4; ++j) {
                    f32x4 xv = *(const f32x4*)&hA[(k0 + j)*LD + pg*4];
                    acc += xv * wv[j];
                }
            }
            float bb = (float)bf2[n*64 + og];
            f32x4 hv;
            #pragma unroll
            for (int r = 0; r < 4; ++r) hv[r] = fmaxf(acc[r] + bb, 0.f);
            *(f32x4*)&xs[og*LD + pg*4] = hv;
        }
        __syncthreads();

        // ---- L3: xs rows 0..63 -> hA
        {
            const T* wr = Wf3 + (size_t)(n*64 + og) * 64;
            f32x4 acc = {};
            #pragma unroll 8
            for (int k0 = 0; k0 < 64; k0 += 4) {
                f32x4 wv = ld4(wr + k0);
                #pragma unroll
                for (int j = 0; j < 4; ++j) {
                    f32x4 xv = *(const f32x4*)&xs[(k0 + j)*LD + pg*4];
                    acc += xv * wv[j];
                }
            }
            float bb = (float)bf3[n*64 + og];
            f32x4 hv;
            #pragma unroll
            for (int r = 0; r < 4; ++r) hv[r] = fmaxf(acc[r] + bb, 0.f);
            *(f32x4*)&hA[og*LD + pg*4] = hv;
        }
        __syncthreads();

        // ---- async stage of next node's lc
        if (nn < 15) stage_load(n + 1);

        // ---- L4: hA x W4 (4 ch/thread) -> fb, weighted accumulate
        {
            f32x4 wgtv = ld4_nt(wgt + (size_t)n*NPTS + p0 + pg*4);
            const T* W4b = Wf4 + ((size_t)n*256 + og*4) * 64;
            const T* b4  = bf4 + n*256 + og*4;
            f32x4 acc[4] = {};
            #pragma unroll 8
            for (int k0 = 0; k0 < 64; k0 += 4) {
                f32x4 wv[4];
                #pragma unroll
                for (int c = 0; c < 4; ++c) wv[c] = ld4(W4b + (size_t)c*64 + k0);
                #pragma unroll
                for (int j = 0; j < 4; ++j) {
                    f32x4 xv = *(const f32x4*)&hA[(k0 + j)*LD + pg*4];
                    #pragma unroll
                    for (int c = 0; c < 4; ++c)
                        acc[c] += xv * wv[c][j];
                }
            }
            #pragma unroll
            for (int c = 0; c < 4; ++c) {
                float bb = (float)b4[c];
                #pragma unroll
                for (int r = 0; r < 4; ++r)
                    fb[c][r] += fmaxf(acc[c][r] + bb, 0.f) * wgtv[r];
            }
        }
        __syncthreads();
        if (nn < 15) { stage_write(n + 1); __syncthreads(); }
    }

    // ---- output: 4 passes of 64 ch; transpose via LDS, coalesced nt store
    int sl = g & smask;
    float* dst = slices + (size_t)sl * NPTS * 256;
    float* tbuf = smem;   // 64 rows x 68 = 17.4 KB, fits in xs region
    #pragma unroll 1
    for (int q = 0; q < 4; ++q) {
        if (q) __syncthreads();
        if ((og >> 4) == q) {
            #pragma unroll
            for (int c = 0; c < 4; ++c)
                #pragma unroll
                for (int r = 0; r < 4; ++r)
                    tbuf[(pg*4 + r)*68 + (og & 15)*4 + c] = fb[c][r];
        }
        __syncthreads();
        int pt = tid >> 4, c4 = (tid & 15) * 4;
        f32x4 val = *(const f32x4*)&tbuf[pt*68 + c4];
        size_t o = ((size_t)(p0 + pt))*256 + q*64 + c4;
        if (smask == 7) {
            __builtin_nontemporal_store(val, (f32x4*)&dst[o]);
        } else {
            #pragma unroll
            for (int j = 0; j < 4; ++j) atomicAdd(&dst[o + j], val[j]);
        }
    }
}

// in-place: slices[0] += slices[1..n-1]
template<int WANT>
__global__ __launch_bounds__(256) void k_reduce(
    float* __restrict__ slices, int nslice, const int* __restrict__ flag)
{
    if (*flag != WANT) return;
    size_t t = (size_t)(blockIdx.x*256 + threadIdx.x) * 4;
    f32x4 s = *(const f32x4*)&slices[t];
    for (int gg = 1; gg < nslice; ++gg)
        s += __builtin_nontemporal_load((const f32x4*)&slices[(size_t)gg*NPTS*256 + t]);
    *(f32x4*)&slices[t] = s;
}

__global__ __launch_bounds__(256) void k_zero_fb(float* __restrict__ fb)
{
    fb[(size_t)blockIdx.x*256 + threadIdx.x] = 0.f;
}

// ---------- Nerf head (verified, unchanged; f_blend := slices[0]) ----------
template<typename T, int WANT>
__global__ __launch_bounds__(256) void k_head_t(
    const float* __restrict__ f_blend,
    const T* __restrict__ Wc1, const T* __restrict__ bc1,
    const T* __restrict__ Wc2, const T* __restrict__ bc2,
    const T* __restrict__ Wd1, const T* __restrict__ bd1,
    T* __restrict__ out_c, T* __restrict__ out_d,
    const int* __restrict__ flag)
{
    if (*flag != WANT) return;
    int t = blockIdx.x * 256 + threadIdx.x;
    int p = t >> 6, j = t & 63;
    const float* fb = f_blend + (size_t)p * 256;

    float a = (float)bc1[j];
    #pragma unroll 8
    for (int c = 0; c < 256; ++c)
        a += fb[c] * (float)Wc1[c*64 + j];
    float nc = fmaxf(a, 0.f);

    float s0 = nc * (float)Wc2[j*3 + 0];
    float s1 = nc * (float)Wc2[j*3 + 1];
    float s2 = nc * (float)Wc2[j*3 + 2];
    float sd = 0.f;
    #pragma unroll
    for (int u = 0; u < 4; ++u) {
        int c = j*4 + u;
        sd += fb[c] * (float)Wd1[c];
    }
    #pragma unroll
    for (int off = 32; off > 0; off >>= 1) {
        s0 += __shfl_down(s0, off);
        s1 += __shfl_down(s1, off);
        s2 += __shfl_down(s2, off);
        sd += __shfl_down(sd, off);
    }
    if (j == 0) {
        out_c[p*3 + 0] = (T)(s0 + (float)bc2[0]);
        out_c[p*3 + 1] = (T)(s1 + (float)bc2[1]);
        out_c[p*3 + 2] = (T)(s2 + (float)bc2[2]);
        out_d[p]       = (T)fmaxf(sd + (float)bd1[0], 0.f);
    }
}

extern "C" void kernel_launch(void* const* d_in, const int* in_sizes, int n_in,
                              void* d_out, int out_size, void* d_ws, size_t ws_size,
                              hipStream_t stream)
{
    const size_t SLICE_BYTES = (size_t)NPTS * 256 * 4;       // 2.10 MB
    const size_t W1P_BYTES   = (size_t)128 * 64 * 96 * 4;    // 3.15 MB
    const size_t WGT_BYTES   = (size_t)128 * NPTS * 4;       // 1.05 MB

    size_t base = ((WGT_BYTES + 255) & ~(size_t)255) + 256 + 4096;  // wgt + flag + slack
    bool use_w1p = false; int nslice = 1;
    if      (base + W1P_BYTES + 8*SLICE_BYTES <= ws_size) { use_w1p = true;  nslice = 8; }
    else if (base + 8*SLICE_BYTES <= ws_size)             { use_w1p = false; nslice = 8; }
    else if (base + W1P_BYTES + 4*SLICE_BYTES <= ws_size) { use_w1p = true;  nslice = 4; }
    else if (base + 4*SLICE_BYTES <= ws_size)             { use_w1p = false; nslice = 4; }
    else if (base + 2*SLICE_BYTES <= ws_size)             { use_w1p = false; nslice = 2; }
    else                                                  { use_w1p = false; nslice = 1; }
    int smask = nslice - 1;

    char* wsp = (char*)d_ws;
    auto alloc = [&](size_t bytes) { char* r = wsp; wsp += (bytes + 255) & ~(size_t)255; return r; };
    float* wgt  = (float*)alloc(WGT_BYTES);
    int*   flag = (int*)  alloc(256);
    float* W1p  = use_w1p ? (float*)alloc(W1P_BYTES) : nullptr;
    float* slices = (float*)alloc((size_t)nslice * SLICE_BYTES);
    float* f_blend = slices;   // after stores/reduce, slice 0 holds the sum

    hipLaunchKernelGGL(k_sniff, dim3(1), dim3(256), 0, stream, d_in[0], flag);
    if (nslice < 8)   // atomic fallback needs zeroed targets; 8-slice mode is pure overwrite
        hipLaunchKernelGGL(k_zero_fb, dim3(nslice * 2048), dim3(256), 0, stream, slices);

    #define LAUNCH_ALL(T, WANT)                                                         \
    {                                                                                   \
        const T* poses = (const T*)d_in[0];                                             \
        const T* t_ped = (const T*)d_in[1];                                             \
        const T* w     = (const T*)d_in[2];                                             \
        const T* wpts  = (const T*)d_in[3];                                             \
        const T* nodes = (const T*)d_in[4];                                             \
        const T* lc    = (const T*)d_in[5];                                             \
        const T* Wec1  = (const T*)d_in[6];  const T* bec1 = (const T*)d_in[7];         \
        const T* Wec21 = (const T*)d_in[8];  const T* bec21= (const T*)d_in[9];         \
        const T* Wec22 = (const T*)d_in[10]; const T* bec22= (const T*)d_in[11];        \
        const T* Wdc1  = (const T*)d_in[12]; const T* bdc1 = (const T*)d_in[13];        \
        const T* Wdc21 = (const T*)d_in[14]; const T* bdc21= (const T*)d_in[15];        \
        const T* Wdc22 = (const T*)d_in[16]; const T* bdc22= (const T*)d_in[17];        \
        const T* Wf1   = (const T*)d_in[18]; const T* bf1  = (const T*)d_in[19];        \
        const T* Wf2   = (const T*)d_in[20]; const T* bf2  = (const T*)d_in[21];        \
        const T* Wf3   = (const T*)d_in[22]; const T* bf3  = (const T*)d_in[23];        \
        const T* Wf4   = (const T*)d_in[24]; const T* bf4  = (const T*)d_in[25];        \
        const T* Wc1   = (const T*)d_in[26]; const T* bc1  = (const T*)d_in[27];        \
        const T* Wc2   = (const T*)d_in[28]; const T* bc2  = (const T*)d_in[29];        \
        const T* Wd1   = (const T*)d_in[30]; const T* bd1  = (const T*)d_in[31];        \
        T* out = (T*)d_out;                                                             \
        T* out_c      = out;                                                            \
        T* out_d      = out + 6144;                                                     \
        T* out_ei     = out + 8192;                                                     \
        T* out_delta  = out + 12288;                                                    \
        T* out_mean   = out + 12672;                                                    \
        T* out_logvar = out + 13696;                                                    \
        hipLaunchKernelGGL((k_encdec_t<T, WANT>), dim3(128), dim3(128), 0, stream,      \
            poses, t_ped, w, Wec1, bec1, Wec21, bec21, Wec22, bec22,                    \
            Wdc1, bdc1, Wdc21, bdc21, Wdc22, bdc22,                                     \
            out_ei, out_delta, out_mean, out_logvar, flag);                             \
        hipLaunchKernelGGL((k_bweights_t<T, WANT>), dim3(8), dim3(256), 0, stream,      \
            wpts, nodes, wgt, flag);                                                    \
        if (use_w1p) {                                                                  \
            hipLaunchKernelGGL((k_w1prep<T, WANT>), dim3(128), dim3(256), 0, stream,    \
                Wf1, W1p, flag);                                                        \
            hipLaunchKernelGGL((k_feat_fast<T, WANT, 1>), dim3(256), dim3(1024), 0,     \
                stream, Wf1, Wf2, Wf3, Wf4, lc, (const T*)out_ei,                       \
                bf1, bf2, bf3, bf4, wgt, W1p, smask, slices, flag);                     \
        } else {                                                                        \
            hipLaunchKernelGGL((k_feat_fast<T, WANT, 0>), dim3(256), dim3(1024), 0,     \
                stream, Wf1, Wf2, Wf3, Wf4, lc, (const T*)out_ei,                       \
                bf1, bf2, bf3, bf4, wgt, W1p, smask, slices, flag);                     \
        }                                                                               \
        if (nslice > 1)                                                                 \
            hipLaunchKernelGGL((k_reduce<WANT>), dim3(512), dim3(256), 0, stream,       \
                slices, nslice, flag);                                                  \
        hipLaunchKernelGGL((k_head_t<T, WANT>), dim3(512), dim3(256), 0, stream,        \
            f_blend, Wc1, bc1, Wc2, bc2, Wd1, bd1, out_c, out_d, flag);                 \
    }

    LAUNCH_ALL(bf16, 1)
    LAUNCH_ALL(float, 0)
    #undef LAUNCH_ALL
}